// Round 14
// baseline (1031.566 us; speedup 1.0000x reference)
//
#include <hip/hip_runtime.h>

// ---- static problem config ----
#define B_ 4
#define Q_ 32
#define D_ 512
#define H_ 8
#define L_ 4
#define P_ 4
#define V_ 12000
#define T_ 16
#define HD_ 64
#define S_ 3840
#define BQ_ 128
#define NSTEP 15
#define NSLAB 94   // ceil(12000/128)

typedef __attribute__((ext_vector_type(8))) short short8;
typedef __attribute__((ext_vector_type(4))) float f32x4;

__device__ inline unsigned short f2bf(float x) {
  union { float f; unsigned u; } v; v.f = x;
  unsigned u = v.u;
  unsigned r = (u + 0x7fffu + ((u >> 16) & 1u)) >> 16;  // RNE
  return (unsigned short)r;
}
__device__ inline float bf2f(unsigned short b) {
  union { unsigned u; float f; } v; v.u = ((unsigned)b) << 16; return v.f;
}
__device__ inline float fast_tanh(float x) {
  x = fminf(fmaxf(x, -15.f), 15.f);
  float e = __expf(2.f * x);
  return (e - 1.f) / (e + 1.f);
}
__device__ inline float sigmoidf_(float x) { return 1.f / (1.f + __expf(-x)); }

// ---------------- shared-memory structs ----------------
#define APAD 40
struct SmemGemm {            // double-buffered, ~40 KB
  unsigned short As0[128 * APAD], Bs0[128 * APAD];
  unsigned short As1[128 * APAD], Bs1[128 * APAD];
};
struct SmemGemmS {           // single-buffered (one-time kernels), ~20 KB
  unsigned short As[128 * APAD], Bs[128 * APAD];
};
struct SmemSample {
  float ctx_s[16][HD_];
  float aw_s[16];
  float wgt_s[16];
  float wred[4][16];
};

// ---------------- GEMM common pieces ----------------
__device__ inline short8 cvt8(float4 v0, float4 v1) {
  short8 p;
  p[0] = (short)f2bf(v0.x); p[1] = (short)f2bf(v0.y);
  p[2] = (short)f2bf(v0.z); p[3] = (short)f2bf(v0.w);
  p[4] = (short)f2bf(v1.x); p[5] = (short)f2bf(v1.y);
  p[6] = (short)f2bf(v1.z); p[7] = (short)f2bf(v1.w);
  return p;
}

__device__ inline void mfma_step(const unsigned short* As, const unsigned short* Bs,
                                 f32x4 acc[4][4], int wm, int wn, int lane) {
  int r15 = lane & 15, koct = (lane >> 4) * 8;
  short8 a[4], b[4];
#pragma unroll
  for (int mf = 0; mf < 4; mf++)
    a[mf] = *(const short8*)(As + (wm * 64 + mf * 16 + r15) * APAD + koct);
#pragma unroll
  for (int nf = 0; nf < 4; nf++)
    b[nf] = *(const short8*)(Bs + (wn * 64 + nf * 16 + r15) * APAD + koct);
#pragma unroll
  for (int mf = 0; mf < 4; mf++)
#pragma unroll
    for (int nf = 0; nf < 4; nf++)
      acc[mf][nf] = __builtin_amdgcn_mfma_f32_16x16x32_bf16(a[mf], b[nf], acc[mf][nf], 0, 0, 0);
}

// Pipelined K-loop: double-buffered LDS, ONE sync/iter, register prefetch.
template <int NT, class FA, class FB>
__device__ inline void gemm_pipe(FA loadA, FB loadB, SmemGemm& sm,
                                 f32x4 acc[4][4], int wm, int wn, int lane, int tid) {
  int r = tid >> 2, ko = (tid & 3) * 8;
  short8 a0, a1, b0, b1;
  loadA(0, a0, a1); loadB(0, b0, b1);
#pragma unroll
  for (int t = 0; t < NT; t++) {
    unsigned short* As = (t & 1) ? sm.As1 : sm.As0;
    unsigned short* Bs = (t & 1) ? sm.Bs1 : sm.Bs0;
    *(short8*)(As + r * APAD + ko) = a0;
    *(short8*)(As + (r + 64) * APAD + ko) = a1;
    *(short8*)(Bs + r * APAD + ko) = b0;
    *(short8*)(Bs + (r + 64) * APAD + ko) = b1;
    short8 na0, na1, nb0, nb1;
    if (t + 1 < NT) { loadA(t + 1, na0, na1); loadB(t + 1, nb0, nb1); }
    __syncthreads();
    mfma_step(As, Bs, acc, wm, wn, lane);
    if (t + 1 < NT) { a0 = na0; a1 = na1; b0 = nb0; b1 = nb1; }
  }
}

// Single-buffered loop (one-time kernels)
template <int NT, class FA, class FB>
__device__ inline void gemm_simple(FA loadA, FB loadB, SmemGemmS& sm,
                                   f32x4 acc[4][4], int wm, int wn, int lane, int tid) {
  int r = tid >> 2, ko = (tid & 3) * 8;
#pragma unroll 2
  for (int t = 0; t < NT; t++) {
    short8 a0, a1, b0, b1;
    loadA(t, a0, a1); loadB(t, b0, b1);
    *(short8*)(sm.As + r * APAD + ko) = a0;
    *(short8*)(sm.As + (r + 64) * APAD + ko) = a1;
    *(short8*)(sm.Bs + r * APAD + ko) = b0;
    *(short8*)(sm.Bs + (r + 64) * APAD + ko) = b1;
    __syncthreads();
    mfma_step(sm.As, sm.Bs, acc, wm, wn, lane);
    __syncthreads();
  }
}

// D layout (HW-verified m89): col = lane&15, row = (lane>>4)*4 + j
__device__ inline void mfma_epilogue(float* __restrict__ out, int ldo, int m0, int n0,
                                     int Nmax, const float* __restrict__ bias,
                                     const unsigned char* __restrict__ mask,
                                     const float* __restrict__ base,
                                     f32x4 acc[4][4], int wm, int wn, int lane) {
  int rb = (lane >> 4) * 4, cb = lane & 15;
#pragma unroll
  for (int nf = 0; nf < 4; nf++) {
    int col = n0 + wn * 64 + nf * 16 + cb;
    if (col >= Nmax) continue;
    float bv = bias ? bias[col] : 0.f;
#pragma unroll
    for (int mf = 0; mf < 4; mf++) {
#pragma unroll
      for (int j = 0; j < 4; j++) {
        int row = m0 + wm * 64 + mf * 16 + rb + j;
        float v = acc[mf][nf][j] + bv;
        if (base) v += base[(size_t)row * ldo + col];
        if (mask && mask[row]) v = 0.f;
        out[(size_t)row * ldo + col] = v;
      }
    }
  }
}

__device__ inline void mfma_epilogue_bf16(unsigned short* __restrict__ out, int ldo, int n0,
                                          f32x4 acc[4][4], int wm, int wn, int lane) {
  int rb = (lane >> 4) * 4, cb = lane & 15;
#pragma unroll
  for (int nf = 0; nf < 4; nf++) {
    int col = n0 + wn * 64 + nf * 16 + cb;
#pragma unroll
    for (int mf = 0; mf < 4; mf++) {
#pragma unroll
      for (int j = 0; j < 4; j++) {
        int row = wm * 64 + mf * 16 + rb + j;
        out[(size_t)row * ldo + col] = f2bf(acc[mf][nf][j]);
      }
    }
  }
}

#define ACC_INIT f32x4 acc[4][4]; { f32x4 z = {0.f,0.f,0.f,0.f}; \
  _Pragma("unroll") for (int i_=0;i_<4;i_++) _Pragma("unroll") for (int j_=0;j_<4;j_++) acc[i_][j_]=z; }

// ================= kernels =================

// one-time: weight converts (Wih/Whh row-PERMUTED) + inits + ctxW transpose + embed gather
__global__ __launch_bounds__(256) void k_prep(const float* __restrict__ logitW,
    const float* __restrict__ Wih, const float* __restrict__ Whh,
    const float* __restrict__ offW, const float* __restrict__ awW,
    const float* __restrict__ hsW, const float* __restrict__ valueW,
    const float* __restrict__ query, const float* __restrict__ ctxW,
    const int* __restrict__ seq, const float* __restrict__ embedW,
    unsigned short* __restrict__ logitWbf, unsigned short* __restrict__ Wihbf,
    unsigned short* __restrict__ Whhbf, unsigned short* __restrict__ offWbf,
    unsigned short* __restrict__ awWbf, unsigned short* __restrict__ hsWbf,
    unsigned short* __restrict__ valueWbf, unsigned short* __restrict__ qbf,
    float* __restrict__ ctxWT, unsigned short* __restrict__ hall, float* __restrict__ c0,
    unsigned short* __restrict__ xembbf) {
  int gi = blockIdx.x * 256 + threadIdx.x;
  const int e0 = 1536000, e1 = e0 + 786432, e2 = e1 + 262144, e3 = e2 + 32768,
            e4 = e3 + 32768, e5 = e4 + 65536, e6 = e5 + 65536, e7 = e6 + 16384;
  const int e8 = e7 + 16384, e9 = e8 + 8192, e10 = e9 + 245760;
  if (gi < e7) {
    const float* src; unsigned short* dst; int lo, dsti;
    if (gi < e0)      { src = logitW; dst = logitWbf; lo = gi; dsti = lo; }
    else if (gi < e1) {
      src = Wih; dst = Wihbf; lo = gi - e0;
      int row = lo / 384, c4 = lo - row * 384;
      int g = row >> 9, d = row & 511, n = d >> 5, rr = d & 31;
      dsti = (n * 128 + g * 32 + rr) * 384 + c4;
    }
    else if (gi < e2) {
      src = Whh; dst = Whhbf; lo = gi - e1;
      int row = lo >> 7, c4 = lo & 127;
      int g = row >> 9, d = row & 511, n = d >> 5, rr = d & 31;
      dsti = (n * 128 + g * 32 + rr) * 128 + c4;
    }
    else if (gi < e3) { src = offW;   dst = offWbf;   lo = gi - e2; dsti = lo; }
    else if (gi < e4) { src = awW;    dst = awWbf;    lo = gi - e3; dsti = lo; }
    else if (gi < e5) { src = hsW;    dst = hsWbf;    lo = gi - e4; dsti = lo; }
    else if (gi < e6) { src = valueW; dst = valueWbf; lo = gi - e5; dsti = lo; }
    else              { src = query;  dst = qbf;      lo = gi - e6; dsti = lo; }
    float4 v = ((const float4*)src)[lo];
    ushort4 o;
    o.x = f2bf(v.x); o.y = f2bf(v.y); o.z = f2bf(v.z); o.w = f2bf(v.w);
    ((ushort4*)dst)[dsti] = o;
  } else if (gi < e8) {
    int i = gi - e7;
    ushort4 z4; z4.x = 0; z4.y = 0; z4.z = 0; z4.w = 0;
    ((ushort4*)hall)[i] = z4;            // hall slot 0 = h_0 = 0
    float4 z = {0.f, 0.f, 0.f, 0.f};
    ((float4*)c0)[i] = z;
  } else if (gi < e9) {
    int i = gi - e8;
    int k = i >> 7, d4 = i & 127;
    float4 o;
    o.x = ctxW[(d4 * 4 + 0) * 64 + k];
    o.y = ctxW[(d4 * 4 + 1) * 64 + k];
    o.z = ctxW[(d4 * 4 + 2) * 64 + k];
    o.w = ctxW[(d4 * 4 + 3) * 64 + k];
    ((float4*)ctxWT)[k * 128 + d4] = o;
  } else if (gi < e10) {
    int i = gi - e9;
    int row = i >> 7, d4 = i & 127;
    int t = row >> 7, bq = row & 127;
    int tok = seq[bq * T_ + t];
    float4 v = ((const float4*)embedW)[(size_t)tok * 128 + d4];
    ushort4 o;
    o.x = f2bf(v.x); o.y = f2bf(v.y); o.z = f2bf(v.z); o.w = f2bf(v.w);
    ((ushort4*)xembbf)[(size_t)row * 128 + d4] = o;
  }
}

// one-time: value = enc @ valueW^T + b (masked), 480 blocks XCD-swizzled
__global__ __launch_bounds__(256) void k_value(const float* __restrict__ enc,
    const unsigned short* __restrict__ valueWbf, const float* __restrict__ valueb,
    const unsigned char* __restrict__ mask, float* __restrict__ value) {
  __shared__ SmemGemmS sm;
  int blk = blockIdx.x;
  int xcd = blk & 7, j = blk >> 3;
  int m0 = (xcd * 15 + (j >> 2)) * 128, n0 = (j & 3) * 128;
  int tid = threadIdx.x;
  int lane = tid & 63, w = tid >> 6, wm = w >> 1, wn = w & 1;
  int r = tid >> 2, ko = (tid & 3) * 8;
  ACC_INIT;
  gemm_simple<16>(
    [&](int t, short8& x, short8& y) {
      const float4* s0 = (const float4*)(enc + (size_t)(m0 + r) * 512 + t * 32 + ko);
      const float4* s1 = (const float4*)(enc + (size_t)(m0 + r + 64) * 512 + t * 32 + ko);
      x = cvt8(s0[0], s0[1]); y = cvt8(s1[0], s1[1]);
    },
    [&](int t, short8& x, short8& y) {
      x = *(const short8*)(valueWbf + (size_t)(n0 + r) * 512 + t * 32 + ko);
      y = *(const short8*)(valueWbf + (size_t)(n0 + r + 64) * 512 + t * 32 + ko);
    },
    sm, acc, wm, wn, lane, tid);
  mfma_epilogue(value, 512, m0, n0, 512, valueb, mask, nullptr, acc, wm, wn, lane);
}

// one-time: qproj (2 blocks) + gates_pre (240 blocks, XCD-swizzled, permuted Wih)
__global__ __launch_bounds__(256) void k_qg(const unsigned short* __restrict__ qbf,
    const unsigned short* __restrict__ offWbf, const float* __restrict__ offb,
    const unsigned short* __restrict__ awWbf, const float* __restrict__ awb,
    float* __restrict__ off_base, float* __restrict__ aw_base,
    const unsigned short* __restrict__ xembbf,
    const unsigned short* __restrict__ Wihbf, unsigned short* __restrict__ gates_base) {
  __shared__ SmemGemmS sm;
  int blk = blockIdx.x;
  int tid = threadIdx.x;
  int lane = tid & 63, w = tid >> 6, wm = w >> 1, wn = w & 1;
  int r = tid >> 2, ko = (tid & 3) * 8;
  if (blk < 2) {
    const unsigned short* Bw = blk ? awWbf : offWbf;
    const float* bias = blk ? awb : offb;
    float* out = blk ? aw_base : off_base;
    ACC_INIT;
    gemm_simple<16>(
      [&](int t, short8& x, short8& y) {
        x = *(const short8*)(qbf + (size_t)r * 512 + t * 32 + ko);
        y = *(const short8*)(qbf + (size_t)(r + 64) * 512 + t * 32 + ko);
      },
      [&](int t, short8& x, short8& y) {
        x = *(const short8*)(Bw + (size_t)r * 1024 + 512 + t * 32 + ko);
        y = *(const short8*)(Bw + (size_t)(r + 64) * 1024 + 512 + t * 32 + ko);
      },
      sm, acc, wm, wn, lane, tid);
    mfma_epilogue(out, 128, 0, 0, 128, bias, nullptr, nullptr, acc, wm, wn, lane);
  } else {
    int g = blk - 2;
    int xcd = g & 7, j = g >> 3;
    int n0 = (xcd * 2 + (j >= 15)) * 128;
    int st = (j >= 15) ? (j - 15) : j;
    const unsigned short* xa = xembbf + (size_t)(st * 128) * 512;
    ACC_INIT;
    gemm_simple<32>(
      [&](int t, short8& x, short8& y) {
        const unsigned short* src = (t < 16) ? xa : qbf;
        int kk = (t < 16) ? t * 32 : (t - 16) * 32;
        x = *(const short8*)(src + (size_t)r * 512 + kk + ko);
        y = *(const short8*)(src + (size_t)(r + 64) * 512 + kk + ko);
      },
      [&](int t, short8& x, short8& y) {
        int kk = (t < 16) ? t * 32 : 1024 + (t - 16) * 32;
        x = *(const short8*)(Wihbf + (size_t)(n0 + r) * 1536 + kk + ko);
        y = *(const short8*)(Wihbf + (size_t)(n0 + r + 64) * 1536 + kk + ko);
      },
      sm, acc, wm, wn, lane, tid);
    mfma_epilogue_bf16(gates_base + (size_t)st * 128 * 2048, 2048, n0, acc, wm, wn, lane);
  }
}

// per-step: deformable sampling + tanh additive attention (1024 blocks)
__global__ __launch_bounds__(256) void k_sample(const float* __restrict__ value,
    const float* __restrict__ off_src, const float* __restrict__ aw_src,
    const float* __restrict__ hp_src, int hstride,
    const float* __restrict__ refp, const float* __restrict__ vrat,
    const float* __restrict__ ctxWT, const float* __restrict__ ctxb,
    const float* __restrict__ alphaW, const float* __restrict__ alphab,
    unsigned short* __restrict__ attnbf) {
  __shared__ SmemSample sm;
  int blk = blockIdx.x;
  int bq = blk >> 3, h = blk & 7;
  int b = bq >> 5;
  int tid = threadIdx.x;
  int lane = tid & 63, wid = tid >> 6;

  if (tid < 16) {
    float v = aw_src[bq * 128 + h * 16 + tid];
    float m = v;
#pragma unroll
    for (int o = 8; o; o >>= 1) m = fmaxf(m, __shfl_xor(m, o, 16));
    float e = __expf(v - m);
    float s = e;
#pragma unroll
    for (int o = 8; o; o >>= 1) s += __shfl_xor(s, o, 16);
    sm.aw_s[tid] = e / s;
  }
  __syncthreads();

  {
    const int TSv[4] = {2048, 1024, 512, 256};
    const int LSv[4] = {0, 2048, 3072, 3584};
    float ref = refp[bq];
    int hd = tid & 63;
#pragma unroll
    for (int pp = 0; pp < 4; pp++) {
      int p = pp * 4 + (tid >> 6);
      int l = p >> 2;
      int Tl = TSv[l];
      float off = off_src[bq * 128 + h * 16 + p];
      float loc = ref * vrat[b * L_ + l] + off / (float)Tl;
      float x = loc * (float)Tl - 0.5f;
      float x0 = floorf(x);
      float wf = x - x0;
      int i0 = (int)x0;
      const float* vb = value + ((size_t)(b * S_ + LSv[l]) * D_) + h * HD_ + hd;
      float v0 = (i0 >= 0 && i0 < Tl) ? vb[(size_t)i0 * D_] : 0.f;
      float v1 = (i0 + 1 >= 0 && i0 + 1 < Tl) ? vb[(size_t)(i0 + 1) * D_] : 0.f;
      sm.ctx_s[p][hd] = (v0 * (1.f - wf) + v1 * wf) * sm.aw_s[p];
    }
  }
  __syncthreads();

  float2 sacc[16];
#pragma unroll
  for (int p = 0; p < 16; p++) { sacc[p].x = 0.f; sacc[p].y = 0.f; }
  for (int k4 = 0; k4 < 16; k4++) {
    float2 wv[4];
#pragma unroll
    for (int kk = 0; kk < 4; kk++)
      wv[kk] = *(const float2*)(ctxWT + (k4 * 4 + kk) * 512 + 2 * tid);
#pragma unroll
    for (int p = 0; p < 16; p++) {
      float4 c = *(const float4*)(&sm.ctx_s[p][k4 * 4]);
      sacc[p].x += c.x * wv[0].x + c.y * wv[1].x + c.z * wv[2].x + c.w * wv[3].x;
      sacc[p].y += c.x * wv[0].y + c.y * wv[1].y + c.z * wv[2].y + c.w * wv[3].y;
    }
  }

  {
    float2 cb = *(const float2*)(ctxb + 2 * tid);
    float2 hp = *(const float2*)(hp_src + (size_t)hstride * bq + 2 * tid);
    float2 al = *(const float2*)(alphaW + 2 * tid);
    float part[16];
#pragma unroll
    for (int p = 0; p < 16; p++)
      part[p] = al.x * fast_tanh(sacc[p].x + cb.x + hp.x) +
                al.y * fast_tanh(sacc[p].y + cb.y + hp.y);
#pragma unroll
    for (int o = 32; o; o >>= 1)
#pragma unroll
      for (int p = 0; p < 16; p++) part[p] += __shfl_xor(part[p], o, 64);
    if (lane == 0)
#pragma unroll
      for (int p = 0; p < 16; p++) sm.wred[wid][p] = part[p];
  }
  __syncthreads();
  if (tid < 16) {
    float v = sm.wred[0][tid] + sm.wred[1][tid] + sm.wred[2][tid] + sm.wred[3][tid] + alphab[0];
    float m = v;
#pragma unroll
    for (int o = 8; o; o >>= 1) m = fmaxf(m, __shfl_xor(m, o, 16));
    float e = __expf(v - m);
    float s = e;
#pragma unroll
    for (int o = 8; o; o >>= 1) s += __shfl_xor(s, o, 16);
    sm.wgt_s[tid] = e / s;
  }
  __syncthreads();
  if (tid < 64) {
    float a = 0.f;
#pragma unroll
    for (int pi = 0; pi < 16; pi++) a += sm.wgt_s[pi] * sm.ctx_s[pi][tid];
    attnbf[bq * D_ + h * HD_ + tid] = f2bf(a);
  }
}

// per-step LSTM gates, split-K x8: K=1024 over [attn|h], 8 chunks of 128
__global__ __launch_bounds__(256) void k_lstm_gemm(
    const unsigned short* __restrict__ attnbf, const unsigned short* __restrict__ hcur,
    const unsigned short* __restrict__ Wihbf, const unsigned short* __restrict__ Whhbf,
    float* __restrict__ gpart) {
  __shared__ SmemGemm sm;
  int tid = threadIdx.x;
  int lane = tid & 63, w = tid >> 6, wm = w >> 1, wn = w & 1;
  int r = tid >> 2, ko = (tid & 3) * 8;
  int n0 = blockIdx.x * 128;
  int kc = blockIdx.y;                // 0..7
  const unsigned short* Asrc = (kc < 4) ? (attnbf + kc * 128) : (hcur + (kc - 4) * 128);
  const unsigned short* Bsrc = (kc < 4) ? (Wihbf + (size_t)n0 * 1536 + 512 + kc * 128)
                                        : (Whhbf + (size_t)n0 * 512 + (kc - 4) * 128);
  int ldB = (kc < 4) ? 1536 : 512;
  ACC_INIT;
  gemm_pipe<4>(
    [&](int t, short8& x, short8& y) {
      x = *(const short8*)(Asrc + (size_t)r * 512 + t * 32 + ko);
      y = *(const short8*)(Asrc + (size_t)(r + 64) * 512 + t * 32 + ko);
    },
    [&](int t, short8& x, short8& y) {
      x = *(const short8*)(Bsrc + (size_t)r * ldB + t * 32 + ko);
      y = *(const short8*)(Bsrc + (size_t)(r + 64) * ldB + t * 32 + ko);
    },
    sm, acc, wm, wn, lane, tid);
  mfma_epilogue(gpart + (size_t)kc * 262144, 2048, 0, n0, 2048,
                nullptr, nullptr, nullptr, acc, wm, wn, lane);
}

// LSTM cell: fused split-K(8) reduce + base add + nonlinearity (permuted gate columns)
__global__ __launch_bounds__(256) void k_cell(const float* __restrict__ gpart,
    const unsigned short* __restrict__ gbase_t,
    const float* __restrict__ c, float* __restrict__ cn, unsigned short* __restrict__ hout) {
  int idx = blockIdx.x * 256 + threadIdx.x;
  int bq = idx >> 9, d = idx & 511;
  int n = d >> 5, rr = d & 31;
  size_t rowoff = (size_t)bq * 2048 + n * 128 + rr;
  float g4[4];
#pragma unroll
  for (int gate = 0; gate < 4; gate++) {
    size_t off = rowoff + gate * 32;
    float s = bf2f(gbase_t[off]);
#pragma unroll
    for (int k = 0; k < 8; k++) s += gpart[(size_t)k * 262144 + off];
    g4[gate] = s;
  }
  float cc = c[idx];
  float c2 = sigmoidf_(g4[1]) * cc + sigmoidf_(g4[0]) * fast_tanh(g4[2]);
  float h2 = sigmoidf_(g4[3]) * fast_tanh(c2);
  cn[idx] = c2;
  hout[idx] = f2bf(h2);
}

// per-step projections: off/aw (h half) + hproj; 6 blocks
__global__ __launch_bounds__(256) void k_pre(const unsigned short* __restrict__ hbf,
    const unsigned short* __restrict__ offWbf, const unsigned short* __restrict__ awWbf,
    const unsigned short* __restrict__ hsWbf, const float* __restrict__ hsb,
    const float* __restrict__ off_base, const float* __restrict__ aw_base,
    float* __restrict__ offo, float* __restrict__ awo, float* __restrict__ hpo) {
  __shared__ SmemGemm sm;
  int blk = blockIdx.x;
  const unsigned short* Bw; const float* bias; const float* base;
  float* out; int ldkB, n0, ldo;
  if (blk == 0)      { Bw = offWbf; bias = nullptr; base = off_base; out = offo; ldkB = 1024; n0 = 0; ldo = 128; }
  else if (blk == 1) { Bw = awWbf;  bias = nullptr; base = aw_base;  out = awo;  ldkB = 1024; n0 = 0; ldo = 128; }
  else { Bw = hsWbf; bias = hsb; base = nullptr; out = hpo; ldkB = 512; n0 = (blk - 2) * 128; ldo = 512; }
  int tid = threadIdx.x;
  int lane = tid & 63, w = tid >> 6, wm = w >> 1, wn = w & 1;
  int r = tid >> 2, ko = (tid & 3) * 8;
  ACC_INIT;
  gemm_pipe<16>(
    [&](int t, short8& x, short8& y) {
      x = *(const short8*)(hbf + (size_t)r * 512 + t * 32 + ko);
      y = *(const short8*)(hbf + (size_t)(r + 64) * 512 + t * 32 + ko);
    },
    [&](int t, short8& x, short8& y) {
      x = *(const short8*)(Bw + (size_t)(n0 + r) * ldkB + t * 32 + ko);
      y = *(const short8*)(Bw + (size_t)(n0 + r + 64) * ldkB + t * 32 + ko);
    },
    sm, acc, wm, wn, lane, tid);
  mfma_epilogue(out, ldo, 0, n0, ldo, bias, nullptr, base, acc, wm, wn, lane);
}

// pass 1: logits GEMM, PARTIALS ONLY (no logits write).
// Grid 1416, XCD-chunk swizzle. Partials layout [t][slab][row] (coalesced).
__global__ __launch_bounds__(256) void k_lse_gemm(
    const unsigned short* __restrict__ logitWbf, const float* __restrict__ logitb,
    const unsigned short* __restrict__ hall,
    float* __restrict__ m_sb, float* __restrict__ s_sb) {
  __shared__ SmemGemm sm;
  __shared__ float mred[128][2], sred[128][2];
  int blk = blockIdx.x;
  int swz = (blk & 7) * 177 + (blk >> 3);
  if (swz >= NSLAB * NSTEP) return;
  int slab = swz / NSTEP, t = swz % NSTEP;
  int n0 = slab * 128;
  int tid = threadIdx.x;
  int lane = tid & 63, w = tid >> 6, wm = w >> 1, wn = w & 1;
  int r = tid >> 2, ko = (tid & 3) * 8;
  const unsigned short* hn = hall + (size_t)(t + 1) * 65536;
  bool ok0 = (n0 + r) < V_, ok1 = (n0 + r + 64) < V_;
  ACC_INIT;
  gemm_pipe<16>(
    [&](int tt, short8& x, short8& y) {
      x = *(const short8*)(hn + (size_t)r * 512 + tt * 32 + ko);
      y = *(const short8*)(hn + (size_t)(r + 64) * 512 + tt * 32 + ko);
    },
    [&](int tt, short8& x, short8& y) {
      short8 z = {0, 0, 0, 0, 0, 0, 0, 0};
      x = ok0 ? *(const short8*)(logitWbf + (size_t)(n0 + r) * 512 + tt * 32 + ko) : z;
      y = ok1 ? *(const short8*)(logitWbf + (size_t)(n0 + r + 64) * 512 + tt * 32 + ko) : z;
    },
    sm, acc, wm, wn, lane, tid);
  int rb = (lane >> 4) * 4, cb = lane & 15;
#pragma unroll
  for (int mf = 0; mf < 4; mf++) {
#pragma unroll
    for (int j = 0; j < 4; j++) {
      int row = wm * 64 + mf * 16 + rb + j;
      float vv[4];
      float mx = -3.4e38f;
#pragma unroll
      for (int nf = 0; nf < 4; nf++) {
        int col = n0 + wn * 64 + nf * 16 + cb;
        vv[nf] = (col < V_) ? (acc[mf][nf][j] + logitb[col]) : -3.4e38f;
        mx = fmaxf(mx, vv[nf]);
      }
#pragma unroll
      for (int o = 8; o; o >>= 1) mx = fmaxf(mx, __shfl_xor(mx, o, 16));
      float sme = 0.f;
#pragma unroll
      for (int nf = 0; nf < 4; nf++) sme += (vv[nf] > -3.0e38f) ? __expf(vv[nf] - mx) : 0.f;
#pragma unroll
      for (int o = 8; o; o >>= 1) sme += __shfl_xor(sme, o, 16);
      if (cb == 0) { mred[row][wn] = mx; sred[row][wn] = sme; }
    }
  }
  __syncthreads();
  if (tid < 128) {
    float m0 = mred[tid][0], m1 = mred[tid][1];
    float M = fmaxf(m0, m1);
    float Ssum = sred[tid][0] * __expf(m0 - M) + sred[tid][1] * __expf(m1 - M);
    m_sb[((size_t)t * 96 + slab) * 128 + tid] = M;
    s_sb[((size_t)t * 96 + slab) * 128 + tid] = Ssum;
  }
}

// pass 2a: combine per-(t,row) slab partials -> lse array (1920 blocks x 64 thr)
__global__ __launch_bounds__(64) void k_lse_red(const float* __restrict__ m_sb,
    const float* __restrict__ s_sb, float* __restrict__ lse_arr) {
  int blk = blockIdx.x;                 // 15*128
  int t = blk >> 7, row = blk & 127;
  int lane = threadIdx.x;               // 64
  float m = -3.4e38f, s = 0.f;
  for (int i = lane; i < NSLAB; i += 64) {
    float mi = m_sb[((size_t)t * 96 + i) * 128 + row];
    float si = s_sb[((size_t)t * 96 + i) * 128 + row];
    float M = fmaxf(m, mi);
    s = s * __expf(m - M) + si * __expf(mi - M);
    m = M;
  }
#pragma unroll
  for (int o = 32; o; o >>= 1) {
    float mo = __shfl_xor(m, o, 64), so = __shfl_xor(s, o, 64);
    float M = fmaxf(m, mo);
    s = s * __expf(m - M) + so * __expf(mo - M);
    m = M;
  }
  if (lane == 0) lse_arr[t * 128 + row] = m + __logf(s);
}

// pass 2b: recompute logits GEMM (identical f32), subtract lse, write final out
__global__ __launch_bounds__(256) void k_logits_out(
    const unsigned short* __restrict__ logitWbf, const float* __restrict__ logitb,
    const unsigned short* __restrict__ hall, const float* __restrict__ lse_arr,
    float* __restrict__ outp) {
  __shared__ SmemGemm sm;
  __shared__ float lse_s[128];
  int blk = blockIdx.x;
  int swz = (blk & 7) * 177 + (blk >> 3);
  if (swz >= NSLAB * NSTEP) return;
  int slab = swz / NSTEP, t = swz % NSTEP;
  int n0 = slab * 128;
  int tid = threadIdx.x;
  if (tid < 128) lse_s[tid] = lse_arr[t * 128 + tid];
  int lane = tid & 63, w = tid >> 6, wm = w >> 1, wn = w & 1;
  int r = tid >> 2, ko = (tid & 3) * 8;
  const unsigned short* hn = hall + (size_t)(t + 1) * 65536;
  bool ok0 = (n0 + r) < V_, ok1 = (n0 + r + 64) < V_;
  ACC_INIT;
  gemm_pipe<16>(
    [&](int tt, short8& x, short8& y) {
      x = *(const short8*)(hn + (size_t)r * 512 + tt * 32 + ko);
      y = *(const short8*)(hn + (size_t)(r + 64) * 512 + tt * 32 + ko);
    },
    [&](int tt, short8& x, short8& y) {
      short8 z = {0, 0, 0, 0, 0, 0, 0, 0};
      x = ok0 ? *(const short8*)(logitWbf + (size_t)(n0 + r) * 512 + tt * 32 + ko) : z;
      y = ok1 ? *(const short8*)(logitWbf + (size_t)(n0 + r + 64) * 512 + tt * 32 + ko) : z;
    },
    sm, acc, wm, wn, lane, tid);
  __syncthreads();   // lse_s visible (also covered by pipe syncs, kept for clarity)
  int rb = (lane >> 4) * 4, cb = lane & 15;
#pragma unroll
  for (int nf = 0; nf < 4; nf++) {
    int col = n0 + wn * 64 + nf * 16 + cb;
    if (col >= V_) continue;
    float bv = logitb[col];
#pragma unroll
    for (int mf = 0; mf < 4; mf++) {
#pragma unroll
      for (int j = 0; j < 4; j++) {
        int row = wm * 64 + mf * 16 + rb + j;
        outp[((size_t)row * NSTEP + t) * V_ + col] = acc[mf][nf][j] + bv - lse_s[row];
      }
    }
  }
}

// ---------------- host launch ----------------
extern "C" void kernel_launch(void* const* d_in, const int* in_sizes, int n_in,
                              void* d_out, int out_size, void* d_ws, size_t ws_size,
                              hipStream_t stream) {
  const int* seq             = (const int*)d_in[0];
  const float* query         = (const float*)d_in[1];
  const float* refp          = (const float*)d_in[2];
  const float* enc           = (const float*)d_in[3];
  const float* vrat          = (const float*)d_in[4];
  const unsigned char* mask  = (const unsigned char*)d_in[5];
  const float* embedW        = (const float*)d_in[8];
  const float* logitW        = (const float*)d_in[9];
  const float* logitb        = (const float*)d_in[10];
  const float* Wih           = (const float*)d_in[11];
  const float* Whh           = (const float*)d_in[12];
  const float* valueW        = (const float*)d_in[13];
  const float* valueb        = (const float*)d_in[14];
  const float* offW          = (const float*)d_in[15];
  const float* offb          = (const float*)d_in[16];
  const float* awW           = (const float*)d_in[17];
  const float* awb           = (const float*)d_in[18];
  const float* ctxW          = (const float*)d_in[19];
  const float* ctxb          = (const float*)d_in[20];
  const float* hsW           = (const float*)d_in[21];
  const float* hsb           = (const float*)d_in[22];
  const float* alphaW        = (const float*)d_in[23];
  const float* alphab        = (const float*)d_in[24];

  char* wp = (char*)d_ws;
  auto alloc_f = [&](size_t n) { float* p = (float*)wp; wp += ((n * 4 + 255) / 256) * 256; return p; };
  auto alloc_u = [&](size_t n) { unsigned short* p = (unsigned short*)wp; wp += ((n * 2 + 255) / 256) * 256; return p; };

  float* value   = alloc_f((size_t)B_ * S_ * D_);
  float* gpart   = alloc_f((size_t)8 * BQ_ * 2048);
  float* hproj   = alloc_f((size_t)BQ_ * D_);
  float* offo    = alloc_f((size_t)BQ_ * 128);
  float* awo     = alloc_f((size_t)BQ_ * 128);
  float* off_base= alloc_f((size_t)BQ_ * 128);
  float* aw_base = alloc_f((size_t)BQ_ * 128);
  float* c0      = alloc_f((size_t)BQ_ * D_);
  float* c1      = alloc_f((size_t)BQ_ * D_);
  float* ctxWT   = alloc_f((size_t)64 * 512);
  float* m_sb    = alloc_f((size_t)NSTEP * 96 * BQ_);
  float* s_sb    = alloc_f((size_t)NSTEP * 96 * BQ_);
  float* lse_arr = alloc_f((size_t)NSTEP * BQ_);
  unsigned short* hall    = alloc_u((size_t)(NSTEP + 1) * BQ_ * D_);  // h_0..h_15
  unsigned short* attnbf  = alloc_u((size_t)BQ_ * D_);
  unsigned short* qbf     = alloc_u((size_t)BQ_ * D_);
  unsigned short* xembbf  = alloc_u((size_t)NSTEP * BQ_ * D_);
  unsigned short* gates_base = alloc_u((size_t)NSTEP * BQ_ * 2048);
  unsigned short* logitWbf = alloc_u((size_t)V_ * D_);
  unsigned short* Wihbf    = alloc_u((size_t)2048 * 1536);
  unsigned short* Whhbf    = alloc_u((size_t)2048 * 512);
  unsigned short* offWbf   = alloc_u((size_t)128 * 1024);
  unsigned short* awWbf    = alloc_u((size_t)128 * 1024);
  unsigned short* hsWbf    = alloc_u((size_t)512 * 512);
  unsigned short* valueWbf = alloc_u((size_t)512 * 512);

  // one-time
  k_prep<<<11984, 256, 0, stream>>>(logitW, Wih, Whh, offW, awW, hsW, valueW, query, ctxW,
                                    seq, embedW,
                                    logitWbf, Wihbf, Whhbf, offWbf, awWbf, hsWbf,
                                    valueWbf, qbf, ctxWT, hall, c0, xembbf);
  k_value<<<480, 256, 0, stream>>>(enc, valueWbf, valueb, mask, value);
  k_qg<<<242, 256, 0, stream>>>(qbf, offWbf, offb, awWbf, awb, off_base, aw_base,
                                xembbf, Wihbf, gates_base);

  float* cb[2] = {c0, c1};
  float* outp = (float*)d_out;

  // recurrence loop: only small kernels on the critical chain
  for (int t = 0; t < NSTEP; t++) {
    const unsigned short* hcur = hall + (size_t)t * BQ_ * D_;
    unsigned short* hnxt = hall + (size_t)(t + 1) * BQ_ * D_;
    if (t == 0)
      k_sample<<<1024, 256, 0, stream>>>(value, off_base, aw_base, hsb, 0, refp, vrat,
                                         ctxWT, ctxb, alphaW, alphab, attnbf);
    else
      k_sample<<<1024, 256, 0, stream>>>(value, offo, awo, hproj, 512, refp, vrat,
                                         ctxWT, ctxb, alphaW, alphab, attnbf);
    k_lstm_gemm<<<dim3(16, 8), 256, 0, stream>>>(attnbf, hcur, Wihbf, Whhbf, gpart);
    k_cell<<<256, 256, 0, stream>>>(gpart, gates_base + (size_t)t * BQ_ * 2048,
                                    cb[t & 1], cb[(t + 1) & 1], hnxt);
    if (t + 1 < NSTEP)
      k_pre<<<6, 256, 0, stream>>>(hnxt, offWbf, awWbf, hsWbf, hsb,
                                   off_base, aw_base, offo, awo, hproj);
  }

  // logits: lse pass (partials) -> combine -> recompute+subtract+write final
  k_lse_gemm<<<1416, 256, 0, stream>>>(logitWbf, logitb, hall, m_sb, s_sb);
  k_lse_red<<<NSTEP * BQ_, 64, 0, stream>>>(m_sb, s_sb, lse_arr);
  k_logits_out<<<1416, 256, 0, stream>>>(logitWbf, logitb, hall, lse_arr, outp);
}

// Round 15
// 760.214 us; speedup vs baseline: 1.3569x; 1.3569x over previous
//
#include <hip/hip_runtime.h>

// ---- static problem config ----
#define B_ 4
#define Q_ 32
#define D_ 512
#define H_ 8
#define L_ 4
#define P_ 4
#define V_ 12000
#define T_ 16
#define HD_ 64
#define S_ 3840
#define BQ_ 128
#define NSTEP 15
#define NSLAB 94   // ceil(12000/128)

typedef __attribute__((ext_vector_type(8))) short short8;
typedef __attribute__((ext_vector_type(4))) float f32x4;

__device__ inline unsigned short f2bf(float x) {
  union { float f; unsigned u; } v; v.f = x;
  unsigned u = v.u;
  unsigned r = (u + 0x7fffu + ((u >> 16) & 1u)) >> 16;  // RNE
  return (unsigned short)r;
}
__device__ inline float bf2f(unsigned short b) {
  union { unsigned u; float f; } v; v.u = ((unsigned)b) << 16; return v.f;
}
__device__ inline float fast_tanh(float x) {
  x = fminf(fmaxf(x, -15.f), 15.f);
  float e = __expf(2.f * x);
  return (e - 1.f) / (e + 1.f);
}
__device__ inline float sigmoidf_(float x) { return 1.f / (1.f + __expf(-x)); }

// ---------------- shared-memory structs ----------------
#define APAD 40
struct SmemGemm {            // double-buffered, ~40 KB
  unsigned short As0[128 * APAD], Bs0[128 * APAD];
  unsigned short As1[128 * APAD], Bs1[128 * APAD];
};
struct SmemGemmS {           // single-buffered (one-time kernels), ~20 KB
  unsigned short As[128 * APAD], Bs[128 * APAD];
};
struct SmemSample {
  float ctx_s[16][HD_];
  unsigned short ctxbf[16][72];   // bf16 copy for MFMA A-fragments (pad 72)
  float aw_s[16];
  float wgt_s[16];
  float wred[4][16];
};

// ---------------- GEMM common pieces ----------------
__device__ inline short8 cvt8(float4 v0, float4 v1) {
  short8 p;
  p[0] = (short)f2bf(v0.x); p[1] = (short)f2bf(v0.y);
  p[2] = (short)f2bf(v0.z); p[3] = (short)f2bf(v0.w);
  p[4] = (short)f2bf(v1.x); p[5] = (short)f2bf(v1.y);
  p[6] = (short)f2bf(v1.z); p[7] = (short)f2bf(v1.w);
  return p;
}

__device__ inline void mfma_step(const unsigned short* As, const unsigned short* Bs,
                                 f32x4 acc[4][4], int wm, int wn, int lane) {
  int r15 = lane & 15, koct = (lane >> 4) * 8;
  short8 a[4], b[4];
#pragma unroll
  for (int mf = 0; mf < 4; mf++)
    a[mf] = *(const short8*)(As + (wm * 64 + mf * 16 + r15) * APAD + koct);
#pragma unroll
  for (int nf = 0; nf < 4; nf++)
    b[nf] = *(const short8*)(Bs + (wn * 64 + nf * 16 + r15) * APAD + koct);
#pragma unroll
  for (int mf = 0; mf < 4; mf++)
#pragma unroll
    for (int nf = 0; nf < 4; nf++)
      acc[mf][nf] = __builtin_amdgcn_mfma_f32_16x16x32_bf16(a[mf], b[nf], acc[mf][nf], 0, 0, 0);
}

// Pipelined K-loop: double-buffered LDS, ONE sync/iter, register prefetch.
template <int NT, class FA, class FB>
__device__ inline void gemm_pipe(FA loadA, FB loadB, SmemGemm& sm,
                                 f32x4 acc[4][4], int wm, int wn, int lane, int tid) {
  int r = tid >> 2, ko = (tid & 3) * 8;
  short8 a0, a1, b0, b1;
  loadA(0, a0, a1); loadB(0, b0, b1);
#pragma unroll
  for (int t = 0; t < NT; t++) {
    unsigned short* As = (t & 1) ? sm.As1 : sm.As0;
    unsigned short* Bs = (t & 1) ? sm.Bs1 : sm.Bs0;
    *(short8*)(As + r * APAD + ko) = a0;
    *(short8*)(As + (r + 64) * APAD + ko) = a1;
    *(short8*)(Bs + r * APAD + ko) = b0;
    *(short8*)(Bs + (r + 64) * APAD + ko) = b1;
    short8 na0, na1, nb0, nb1;
    if (t + 1 < NT) { loadA(t + 1, na0, na1); loadB(t + 1, nb0, nb1); }
    __syncthreads();
    mfma_step(As, Bs, acc, wm, wn, lane);
    if (t + 1 < NT) { a0 = na0; a1 = na1; b0 = nb0; b1 = nb1; }
  }
}

// Single-buffered loop (one-time kernels)
template <int NT, class FA, class FB>
__device__ inline void gemm_simple(FA loadA, FB loadB, SmemGemmS& sm,
                                   f32x4 acc[4][4], int wm, int wn, int lane, int tid) {
  int r = tid >> 2, ko = (tid & 3) * 8;
#pragma unroll 2
  for (int t = 0; t < NT; t++) {
    short8 a0, a1, b0, b1;
    loadA(t, a0, a1); loadB(t, b0, b1);
    *(short8*)(sm.As + r * APAD + ko) = a0;
    *(short8*)(sm.As + (r + 64) * APAD + ko) = a1;
    *(short8*)(sm.Bs + r * APAD + ko) = b0;
    *(short8*)(sm.Bs + (r + 64) * APAD + ko) = b1;
    __syncthreads();
    mfma_step(sm.As, sm.Bs, acc, wm, wn, lane);
    __syncthreads();
  }
}

// D layout (HW-verified m89): col = lane&15, row = (lane>>4)*4 + j
__device__ inline void mfma_epilogue(float* __restrict__ out, int ldo, int m0, int n0,
                                     int Nmax, const float* __restrict__ bias,
                                     const unsigned char* __restrict__ mask,
                                     const float* __restrict__ base,
                                     f32x4 acc[4][4], int wm, int wn, int lane) {
  int rb = (lane >> 4) * 4, cb = lane & 15;
#pragma unroll
  for (int nf = 0; nf < 4; nf++) {
    int col = n0 + wn * 64 + nf * 16 + cb;
    if (col >= Nmax) continue;
    float bv = bias ? bias[col] : 0.f;
#pragma unroll
    for (int mf = 0; mf < 4; mf++) {
#pragma unroll
      for (int j = 0; j < 4; j++) {
        int row = m0 + wm * 64 + mf * 16 + rb + j;
        float v = acc[mf][nf][j] + bv;
        if (base) v += base[(size_t)row * ldo + col];
        if (mask && mask[row]) v = 0.f;
        out[(size_t)row * ldo + col] = v;
      }
    }
  }
}

__device__ inline void mfma_epilogue_bf16(unsigned short* __restrict__ out, int ldo, int n0,
                                          f32x4 acc[4][4], int wm, int wn, int lane) {
  int rb = (lane >> 4) * 4, cb = lane & 15;
#pragma unroll
  for (int nf = 0; nf < 4; nf++) {
    int col = n0 + wn * 64 + nf * 16 + cb;
#pragma unroll
    for (int mf = 0; mf < 4; mf++) {
#pragma unroll
      for (int j = 0; j < 4; j++) {
        int row = wm * 64 + mf * 16 + rb + j;
        out[(size_t)row * ldo + col] = f2bf(acc[mf][nf][j]);
      }
    }
  }
}

#define ACC_INIT f32x4 acc[4][4]; { f32x4 z = {0.f,0.f,0.f,0.f}; \
  _Pragma("unroll") for (int i_=0;i_<4;i_++) _Pragma("unroll") for (int j_=0;j_<4;j_++) acc[i_][j_]=z; }

// ================= kernels =================

// one-time: weight converts (Wih/Whh row-PERMUTED) + inits + ctxW bf16 + embed gather
__global__ __launch_bounds__(256) void k_prep(const float* __restrict__ logitW,
    const float* __restrict__ Wih, const float* __restrict__ Whh,
    const float* __restrict__ offW, const float* __restrict__ awW,
    const float* __restrict__ hsW, const float* __restrict__ valueW,
    const float* __restrict__ query, const float* __restrict__ ctxW,
    const int* __restrict__ seq, const float* __restrict__ embedW,
    unsigned short* __restrict__ logitWbf, unsigned short* __restrict__ Wihbf,
    unsigned short* __restrict__ Whhbf, unsigned short* __restrict__ offWbf,
    unsigned short* __restrict__ awWbf, unsigned short* __restrict__ hsWbf,
    unsigned short* __restrict__ valueWbf, unsigned short* __restrict__ qbf,
    unsigned short* __restrict__ ctxWbf, unsigned short* __restrict__ hall,
    float* __restrict__ c0, unsigned short* __restrict__ xembbf) {
  int gi = blockIdx.x * 256 + threadIdx.x;
  const int e0 = 1536000, e1 = e0 + 786432, e2 = e1 + 262144, e3 = e2 + 32768,
            e4 = e3 + 32768, e5 = e4 + 65536, e6 = e5 + 65536, e7 = e6 + 16384;
  const int e8 = e7 + 16384, e9 = e8 + 8192, e10 = e9 + 245760;
  if (gi < e7) {
    const float* src; unsigned short* dst; int lo, dsti;
    if (gi < e0)      { src = logitW; dst = logitWbf; lo = gi; dsti = lo; }
    else if (gi < e1) {
      src = Wih; dst = Wihbf; lo = gi - e0;
      int row = lo / 384, c4 = lo - row * 384;
      int g = row >> 9, d = row & 511, n = d >> 5, rr = d & 31;
      dsti = (n * 128 + g * 32 + rr) * 384 + c4;
    }
    else if (gi < e2) {
      src = Whh; dst = Whhbf; lo = gi - e1;
      int row = lo >> 7, c4 = lo & 127;
      int g = row >> 9, d = row & 511, n = d >> 5, rr = d & 31;
      dsti = (n * 128 + g * 32 + rr) * 128 + c4;
    }
    else if (gi < e3) { src = offW;   dst = offWbf;   lo = gi - e2; dsti = lo; }
    else if (gi < e4) { src = awW;    dst = awWbf;    lo = gi - e3; dsti = lo; }
    else if (gi < e5) { src = hsW;    dst = hsWbf;    lo = gi - e4; dsti = lo; }
    else if (gi < e6) { src = valueW; dst = valueWbf; lo = gi - e5; dsti = lo; }
    else              { src = query;  dst = qbf;      lo = gi - e6; dsti = lo; }
    float4 v = ((const float4*)src)[lo];
    ushort4 o;
    o.x = f2bf(v.x); o.y = f2bf(v.y); o.z = f2bf(v.z); o.w = f2bf(v.w);
    ((ushort4*)dst)[dsti] = o;
  } else if (gi < e8) {
    int i = gi - e7;
    ushort4 z4; z4.x = 0; z4.y = 0; z4.z = 0; z4.w = 0;
    ((ushort4*)hall)[i] = z4;            // hall slot 0 = h_0 = 0
    float4 z = {0.f, 0.f, 0.f, 0.f};
    ((float4*)c0)[i] = z;
  } else if (gi < e9) {
    int i = gi - e8;                     // ctxW (512x64) -> bf16 row-major
    float4 v = ((const float4*)ctxW)[i];
    ushort4 o;
    o.x = f2bf(v.x); o.y = f2bf(v.y); o.z = f2bf(v.z); o.w = f2bf(v.w);
    ((ushort4*)ctxWbf)[i] = o;
  } else if (gi < e10) {
    int i = gi - e9;
    int row = i >> 7, d4 = i & 127;
    int t = row >> 7, bq = row & 127;
    int tok = seq[bq * T_ + t];
    float4 v = ((const float4*)embedW)[(size_t)tok * 128 + d4];
    ushort4 o;
    o.x = f2bf(v.x); o.y = f2bf(v.y); o.z = f2bf(v.z); o.w = f2bf(v.w);
    ((ushort4*)xembbf)[(size_t)row * 128 + d4] = o;
  }
}

// one-time: value = enc @ valueW^T + b (masked), 480 blocks XCD-swizzled
__global__ __launch_bounds__(256) void k_value(const float* __restrict__ enc,
    const unsigned short* __restrict__ valueWbf, const float* __restrict__ valueb,
    const unsigned char* __restrict__ mask, float* __restrict__ value) {
  __shared__ SmemGemmS sm;
  int blk = blockIdx.x;
  int xcd = blk & 7, j = blk >> 3;
  int m0 = (xcd * 15 + (j >> 2)) * 128, n0 = (j & 3) * 128;
  int tid = threadIdx.x;
  int lane = tid & 63, w = tid >> 6, wm = w >> 1, wn = w & 1;
  int r = tid >> 2, ko = (tid & 3) * 8;
  ACC_INIT;
  gemm_simple<16>(
    [&](int t, short8& x, short8& y) {
      const float4* s0 = (const float4*)(enc + (size_t)(m0 + r) * 512 + t * 32 + ko);
      const float4* s1 = (const float4*)(enc + (size_t)(m0 + r + 64) * 512 + t * 32 + ko);
      x = cvt8(s0[0], s0[1]); y = cvt8(s1[0], s1[1]);
    },
    [&](int t, short8& x, short8& y) {
      x = *(const short8*)(valueWbf + (size_t)(n0 + r) * 512 + t * 32 + ko);
      y = *(const short8*)(valueWbf + (size_t)(n0 + r + 64) * 512 + t * 32 + ko);
    },
    sm, acc, wm, wn, lane, tid);
  mfma_epilogue(value, 512, m0, n0, 512, valueb, mask, nullptr, acc, wm, wn, lane);
}

// one-time: qproj (2 blocks) + gates_pre (240 blocks, XCD-swizzled, permuted Wih)
__global__ __launch_bounds__(256) void k_qg(const unsigned short* __restrict__ qbf,
    const unsigned short* __restrict__ offWbf, const float* __restrict__ offb,
    const unsigned short* __restrict__ awWbf, const float* __restrict__ awb,
    float* __restrict__ off_base, float* __restrict__ aw_base,
    const unsigned short* __restrict__ xembbf,
    const unsigned short* __restrict__ Wihbf, unsigned short* __restrict__ gates_base) {
  __shared__ SmemGemmS sm;
  int blk = blockIdx.x;
  int tid = threadIdx.x;
  int lane = tid & 63, w = tid >> 6, wm = w >> 1, wn = w & 1;
  int r = tid >> 2, ko = (tid & 3) * 8;
  if (blk < 2) {
    const unsigned short* Bw = blk ? awWbf : offWbf;
    const float* bias = blk ? awb : offb;
    float* out = blk ? aw_base : off_base;
    ACC_INIT;
    gemm_simple<16>(
      [&](int t, short8& x, short8& y) {
        x = *(const short8*)(qbf + (size_t)r * 512 + t * 32 + ko);
        y = *(const short8*)(qbf + (size_t)(r + 64) * 512 + t * 32 + ko);
      },
      [&](int t, short8& x, short8& y) {
        x = *(const short8*)(Bw + (size_t)r * 1024 + 512 + t * 32 + ko);
        y = *(const short8*)(Bw + (size_t)(r + 64) * 1024 + 512 + t * 32 + ko);
      },
      sm, acc, wm, wn, lane, tid);
    mfma_epilogue(out, 128, 0, 0, 128, bias, nullptr, nullptr, acc, wm, wn, lane);
  } else {
    int g = blk - 2;
    int xcd = g & 7, j = g >> 3;
    int n0 = (xcd * 2 + (j >= 15)) * 128;
    int st = (j >= 15) ? (j - 15) : j;
    const unsigned short* xa = xembbf + (size_t)(st * 128) * 512;
    ACC_INIT;
    gemm_simple<32>(
      [&](int t, short8& x, short8& y) {
        const unsigned short* src = (t < 16) ? xa : qbf;
        int kk = (t < 16) ? t * 32 : (t - 16) * 32;
        x = *(const short8*)(src + (size_t)r * 512 + kk + ko);
        y = *(const short8*)(src + (size_t)(r + 64) * 512 + kk + ko);
      },
      [&](int t, short8& x, short8& y) {
        int kk = (t < 16) ? t * 32 : 1024 + (t - 16) * 32;
        x = *(const short8*)(Wihbf + (size_t)(n0 + r) * 1536 + kk + ko);
        y = *(const short8*)(Wihbf + (size_t)(n0 + r + 64) * 1536 + kk + ko);
      },
      sm, acc, wm, wn, lane, tid);
    mfma_epilogue_bf16(gates_base + (size_t)st * 128 * 2048, 2048, n0, acc, wm, wn, lane);
  }
}

// per-step: deformable sampling + tanh additive attention (1024 blocks)
// Phase B uses MFMA: dot[16p x 512d] = ctx(16x64) @ ctxW(512x64)^T
__global__ __launch_bounds__(256) void k_sample(const float* __restrict__ value,
    const float* __restrict__ off_src, const float* __restrict__ aw_src,
    const float* __restrict__ hp_src, int hstride,
    const float* __restrict__ refp, const float* __restrict__ vrat,
    const unsigned short* __restrict__ ctxWbf, const float* __restrict__ ctxb,
    const float* __restrict__ alphaW, const float* __restrict__ alphab,
    unsigned short* __restrict__ attnbf) {
  __shared__ SmemSample sm;
  int blk = blockIdx.x;
  int bq = blk >> 3, h = blk & 7;
  int b = bq >> 5;
  int tid = threadIdx.x;
  int lane = tid & 63, wid = tid >> 6;

  if (tid < 16) {
    float v = aw_src[bq * 128 + h * 16 + tid];
    float m = v;
#pragma unroll
    for (int o = 8; o; o >>= 1) m = fmaxf(m, __shfl_xor(m, o, 16));
    float e = __expf(v - m);
    float s = e;
#pragma unroll
    for (int o = 8; o; o >>= 1) s += __shfl_xor(s, o, 16);
    sm.aw_s[tid] = e / s;
  }
  __syncthreads();

  {  // Phase A: 1-D linear sampling, weighted by aw; store f32 + bf16 copies
    const int TSv[4] = {2048, 1024, 512, 256};
    const int LSv[4] = {0, 2048, 3072, 3584};
    float ref = refp[bq];
    int hd = tid & 63;
#pragma unroll
    for (int pp = 0; pp < 4; pp++) {
      int p = pp * 4 + (tid >> 6);
      int l = p >> 2;
      int Tl = TSv[l];
      float off = off_src[bq * 128 + h * 16 + p];
      float loc = ref * vrat[b * L_ + l] + off / (float)Tl;
      float x = loc * (float)Tl - 0.5f;
      float x0 = floorf(x);
      float wf = x - x0;
      int i0 = (int)x0;
      const float* vb = value + ((size_t)(b * S_ + LSv[l]) * D_) + h * HD_ + hd;
      float v0 = (i0 >= 0 && i0 < Tl) ? vb[(size_t)i0 * D_] : 0.f;
      float v1 = (i0 + 1 >= 0 && i0 + 1 < Tl) ? vb[(size_t)(i0 + 1) * D_] : 0.f;
      float cv = (v0 * (1.f - wf) + v1 * wf) * sm.aw_s[p];
      sm.ctx_s[p][hd] = cv;
      sm.ctxbf[p][hd] = f2bf(cv);
    }
  }
  __syncthreads();

  {  // Phase B: MFMA over this wave's 128 d-columns + alpha*tanh accumulation
    int r15 = lane & 15, koct = (lane >> 4) * 8;
    int rb = (lane >> 4) * 4, cb = lane & 15;
    short8 a0 = *(const short8*)(&sm.ctxbf[r15][koct]);
    short8 a1 = *(const short8*)(&sm.ctxbf[r15][32 + koct]);
    float part0 = 0.f, part1 = 0.f, part2 = 0.f, part3 = 0.f;
#pragma unroll
    for (int nf = 0; nf < 8; nf++) {
      int d0 = wid * 128 + nf * 16;
      const unsigned short* bp = ctxWbf + (size_t)(d0 + r15) * 64;
      short8 b0 = *(const short8*)(bp + koct);
      short8 b1 = *(const short8*)(bp + 32 + koct);
      f32x4 acc = {0.f, 0.f, 0.f, 0.f};
      acc = __builtin_amdgcn_mfma_f32_16x16x32_bf16(a0, b0, acc, 0, 0, 0);
      acc = __builtin_amdgcn_mfma_f32_16x16x32_bf16(a1, b1, acc, 0, 0, 0);
      int d = d0 + cb;
      float add = ctxb[d] + hp_src[(size_t)hstride * bq + d];
      float al = alphaW[d];
      part0 += al * fast_tanh(acc[0] + add);
      part1 += al * fast_tanh(acc[1] + add);
      part2 += al * fast_tanh(acc[2] + add);
      part3 += al * fast_tanh(acc[3] + add);
    }
#pragma unroll
    for (int o = 8; o; o >>= 1) {
      part0 += __shfl_xor(part0, o, 16);
      part1 += __shfl_xor(part1, o, 16);
      part2 += __shfl_xor(part2, o, 16);
      part3 += __shfl_xor(part3, o, 16);
    }
    if (cb == 0) {
      sm.wred[wid][rb + 0] = part0;
      sm.wred[wid][rb + 1] = part1;
      sm.wred[wid][rb + 2] = part2;
      sm.wred[wid][rb + 3] = part3;
    }
  }
  __syncthreads();
  if (tid < 16) {
    float v = sm.wred[0][tid] + sm.wred[1][tid] + sm.wred[2][tid] + sm.wred[3][tid] + alphab[0];
    float m = v;
#pragma unroll
    for (int o = 8; o; o >>= 1) m = fmaxf(m, __shfl_xor(m, o, 16));
    float e = __expf(v - m);
    float s = e;
#pragma unroll
    for (int o = 8; o; o >>= 1) s += __shfl_xor(s, o, 16);
    sm.wgt_s[tid] = e / s;
  }
  __syncthreads();
  if (tid < 64) {
    float a = 0.f;
#pragma unroll
    for (int pi = 0; pi < 16; pi++) a += sm.wgt_s[pi] * sm.ctx_s[pi][tid];
    attnbf[bq * D_ + h * HD_ + tid] = f2bf(a);
  }
}

// per-step LSTM gates, split-K x4: K=1024 over [attn|h] (permuted weights)
__global__ __launch_bounds__(256) void k_lstm_gemm(
    const unsigned short* __restrict__ attnbf, const unsigned short* __restrict__ hcur,
    const unsigned short* __restrict__ Wihbf, const unsigned short* __restrict__ Whhbf,
    float* __restrict__ gpart) {
  __shared__ SmemGemm sm;
  int tid = threadIdx.x;
  int lane = tid & 63, w = tid >> 6, wm = w >> 1, wn = w & 1;
  int r = tid >> 2, ko = (tid & 3) * 8;
  int n0 = blockIdx.x * 128;
  int kc = blockIdx.y;
  const unsigned short* Asrc = (kc < 2) ? (attnbf + kc * 256) : (hcur + (kc - 2) * 256);
  const unsigned short* Bsrc = (kc < 2) ? (Wihbf + (size_t)n0 * 1536 + 512 + kc * 256)
                                        : (Whhbf + (size_t)n0 * 512 + (kc - 2) * 256);
  int ldB = (kc < 2) ? 1536 : 512;
  ACC_INIT;
  gemm_pipe<8>(
    [&](int t, short8& x, short8& y) {
      x = *(const short8*)(Asrc + (size_t)r * 512 + t * 32 + ko);
      y = *(const short8*)(Asrc + (size_t)(r + 64) * 512 + t * 32 + ko);
    },
    [&](int t, short8& x, short8& y) {
      x = *(const short8*)(Bsrc + (size_t)r * ldB + t * 32 + ko);
      y = *(const short8*)(Bsrc + (size_t)(r + 64) * ldB + t * 32 + ko);
    },
    sm, acc, wm, wn, lane, tid);
  mfma_epilogue(gpart + (size_t)kc * 262144, 2048, 0, n0, 2048,
                nullptr, nullptr, nullptr, acc, wm, wn, lane);
}

// LSTM cell: fused split-K(4) reduce + base add + nonlinearity (permuted gate columns)
__global__ __launch_bounds__(256) void k_cell(const float* __restrict__ gpart,
    const unsigned short* __restrict__ gbase_t,
    const float* __restrict__ c, float* __restrict__ cn, unsigned short* __restrict__ hout) {
  int idx = blockIdx.x * 256 + threadIdx.x;
  int bq = idx >> 9, d = idx & 511;
  int n = d >> 5, rr = d & 31;
  size_t rowoff = (size_t)bq * 2048 + n * 128 + rr;
  float g4[4];
#pragma unroll
  for (int gate = 0; gate < 4; gate++) {
    size_t off = rowoff + gate * 32;
    float s = bf2f(gbase_t[off]);
    s += gpart[off] + gpart[262144 + off] + gpart[2 * 262144 + off] + gpart[3 * 262144 + off];
    g4[gate] = s;
  }
  float cc = c[idx];
  float c2 = sigmoidf_(g4[1]) * cc + sigmoidf_(g4[0]) * fast_tanh(g4[2]);
  float h2 = sigmoidf_(g4[3]) * fast_tanh(c2);
  cn[idx] = c2;
  hout[idx] = f2bf(h2);
}

// per-step projections: off/aw (h half) + hproj; 6 blocks
__global__ __launch_bounds__(256) void k_pre(const unsigned short* __restrict__ hbf,
    const unsigned short* __restrict__ offWbf, const unsigned short* __restrict__ awWbf,
    const unsigned short* __restrict__ hsWbf, const float* __restrict__ hsb,
    const float* __restrict__ off_base, const float* __restrict__ aw_base,
    float* __restrict__ offo, float* __restrict__ awo, float* __restrict__ hpo) {
  __shared__ SmemGemm sm;
  int blk = blockIdx.x;
  const unsigned short* Bw; const float* bias; const float* base;
  float* out; int ldkB, n0, ldo;
  if (blk == 0)      { Bw = offWbf; bias = nullptr; base = off_base; out = offo; ldkB = 1024; n0 = 0; ldo = 128; }
  else if (blk == 1) { Bw = awWbf;  bias = nullptr; base = aw_base;  out = awo;  ldkB = 1024; n0 = 0; ldo = 128; }
  else { Bw = hsWbf; bias = hsb; base = nullptr; out = hpo; ldkB = 512; n0 = (blk - 2) * 128; ldo = 512; }
  int tid = threadIdx.x;
  int lane = tid & 63, w = tid >> 6, wm = w >> 1, wn = w & 1;
  int r = tid >> 2, ko = (tid & 3) * 8;
  ACC_INIT;
  gemm_pipe<16>(
    [&](int t, short8& x, short8& y) {
      x = *(const short8*)(hbf + (size_t)r * 512 + t * 32 + ko);
      y = *(const short8*)(hbf + (size_t)(r + 64) * 512 + t * 32 + ko);
    },
    [&](int t, short8& x, short8& y) {
      x = *(const short8*)(Bw + (size_t)(n0 + r) * ldkB + t * 32 + ko);
      y = *(const short8*)(Bw + (size_t)(n0 + r + 64) * ldkB + t * 32 + ko);
    },
    sm, acc, wm, wn, lane, tid);
  mfma_epilogue(out, ldo, 0, n0, ldo, bias, nullptr, base, acc, wm, wn, lane);
}

// batched logits for ALL steps as ONE plain GEMM: writes raw logits into d_out +
// per-(t,row) slab partials. Grid 1416, XCD-chunk swizzle.
__global__ __launch_bounds__(256) void k_logits_big(
    const unsigned short* __restrict__ logitWbf, const float* __restrict__ logitb,
    const unsigned short* __restrict__ hall, float* __restrict__ outp,
    float* __restrict__ m_sb, float* __restrict__ s_sb) {
  __shared__ SmemGemm sm;
  __shared__ float mred[128][2], sred[128][2];
  int blk = blockIdx.x;
  int swz = (blk & 7) * 177 + (blk >> 3);     // XCD-chunked over 1416=8*177
  if (swz >= NSLAB * NSTEP) return;
  int slab = swz / NSTEP, t = swz % NSTEP;
  int n0 = slab * 128;
  int tid = threadIdx.x;
  int lane = tid & 63, w = tid >> 6, wm = w >> 1, wn = w & 1;
  int r = tid >> 2, ko = (tid & 3) * 8;
  const unsigned short* hn = hall + (size_t)(t + 1) * 65536;
  bool ok0 = (n0 + r) < V_, ok1 = (n0 + r + 64) < V_;
  ACC_INIT;
  gemm_pipe<16>(
    [&](int tt, short8& x, short8& y) {
      x = *(const short8*)(hn + (size_t)r * 512 + tt * 32 + ko);
      y = *(const short8*)(hn + (size_t)(r + 64) * 512 + tt * 32 + ko);
    },
    [&](int tt, short8& x, short8& y) {
      short8 z = {0, 0, 0, 0, 0, 0, 0, 0};
      x = ok0 ? *(const short8*)(logitWbf + (size_t)(n0 + r) * 512 + tt * 32 + ko) : z;
      y = ok1 ? *(const short8*)(logitWbf + (size_t)(n0 + r + 64) * 512 + tt * 32 + ko) : z;
    },
    sm, acc, wm, wn, lane, tid);
  int rb = (lane >> 4) * 4, cb = lane & 15;
#pragma unroll
  for (int mf = 0; mf < 4; mf++) {
#pragma unroll
    for (int j = 0; j < 4; j++) {
      int row = wm * 64 + mf * 16 + rb + j;
      float vv[4];
      float mx = -3.4e38f;
#pragma unroll
      for (int nf = 0; nf < 4; nf++) {
        int col = n0 + wn * 64 + nf * 16 + cb;
        bool ok = col < V_;
        float v = ok ? (acc[mf][nf][j] + logitb[col]) : -3.4e38f;
        if (ok) outp[((size_t)row * NSTEP + t) * V_ + col] = v;
        vv[nf] = v;
        mx = fmaxf(mx, v);
      }
#pragma unroll
      for (int o = 8; o; o >>= 1) mx = fmaxf(mx, __shfl_xor(mx, o, 16));
      float sme = 0.f;
#pragma unroll
      for (int nf = 0; nf < 4; nf++) sme += (vv[nf] > -3.0e38f) ? __expf(vv[nf] - mx) : 0.f;
#pragma unroll
      for (int o = 8; o; o >>= 1) sme += __shfl_xor(sme, o, 16);
      if (cb == 0) { mred[row][wn] = mx; sred[row][wn] = sme; }
    }
  }
  __syncthreads();
  if (tid < 128) {
    float m0 = mred[tid][0], m1 = mred[tid][1];
    float M = fmaxf(m0, m1);
    float Ssum = sred[tid][0] * __expf(m0 - M) + sred[tid][1] * __expf(m1 - M);
    m_sb[((size_t)t * 128 + tid) * 96 + slab] = M;
    s_sb[((size_t)t * 128 + tid) * 96 + slab] = Ssum;
  }
}

// final: per (t,row) combine partials -> lse, subtract in-place in d_out
__global__ __launch_bounds__(256) void k_out_all(const float* __restrict__ m_sb,
    const float* __restrict__ s_sb, float* __restrict__ outp) {
  __shared__ float ms[NSLAB], ss[NSLAB];
  __shared__ float lse_s;
  int blk = blockIdx.x;                 // 1920 = 15*128
  int t = blk >> 7, row = blk & 127;
  int tid = threadIdx.x;
  size_t pbase = ((size_t)t * 128 + row) * 96;
  if (tid < NSLAB) { ms[tid] = m_sb[pbase + tid]; ss[tid] = s_sb[pbase + tid]; }
  __syncthreads();
  if (tid < 64) {
    float m = -3.4e38f, s = 0.f;
    for (int i = tid; i < NSLAB; i += 64) {
      float mi = ms[i], si = ss[i];
      float M = fmaxf(m, mi);
      s = s * __expf(m - M) + si * __expf(mi - M);
      m = M;
    }
#pragma unroll
    for (int o = 32; o; o >>= 1) {
      float mo = __shfl_xor(m, o, 64), so = __shfl_xor(s, o, 64);
      float M = fmaxf(m, mo);
      s = s * __expf(m - M) + so * __expf(mo - M);
      m = M;
    }
    if (tid == 0) lse_s = m + __logf(s);
  }
  __syncthreads();
  float lse = lse_s;
  float4* op = (float4*)(outp + ((size_t)row * NSTEP + t) * V_);
  for (int i = tid; i < V_ / 4; i += 256) {
    float4 v = op[i];
    v.x -= lse; v.y -= lse; v.z -= lse; v.w -= lse;
    op[i] = v;
  }
}

// ---------------- host launch ----------------
extern "C" void kernel_launch(void* const* d_in, const int* in_sizes, int n_in,
                              void* d_out, int out_size, void* d_ws, size_t ws_size,
                              hipStream_t stream) {
  const int* seq             = (const int*)d_in[0];
  const float* query         = (const float*)d_in[1];
  const float* refp          = (const float*)d_in[2];
  const float* enc           = (const float*)d_in[3];
  const float* vrat          = (const float*)d_in[4];
  const unsigned char* mask  = (const unsigned char*)d_in[5];
  const float* embedW        = (const float*)d_in[8];
  const float* logitW        = (const float*)d_in[9];
  const float* logitb        = (const float*)d_in[10];
  const float* Wih           = (const float*)d_in[11];
  const float* Whh           = (const float*)d_in[12];
  const float* valueW        = (const float*)d_in[13];
  const float* valueb        = (const float*)d_in[14];
  const float* offW          = (const float*)d_in[15];
  const float* offb          = (const float*)d_in[16];
  const float* awW           = (const float*)d_in[17];
  const float* awb           = (const float*)d_in[18];
  const float* ctxW          = (const float*)d_in[19];
  const float* ctxb          = (const float*)d_in[20];
  const float* hsW           = (const float*)d_in[21];
  const float* hsb           = (const float*)d_in[22];
  const float* alphaW        = (const float*)d_in[23];
  const float* alphab        = (const float*)d_in[24];

  char* wp = (char*)d_ws;
  auto alloc_f = [&](size_t n) { float* p = (float*)wp; wp += ((n * 4 + 255) / 256) * 256; return p; };
  auto alloc_u = [&](size_t n) { unsigned short* p = (unsigned short*)wp; wp += ((n * 2 + 255) / 256) * 256; return p; };

  float* value   = alloc_f((size_t)B_ * S_ * D_);
  float* gpart   = alloc_f((size_t)4 * BQ_ * 2048);
  float* hproj   = alloc_f((size_t)BQ_ * D_);
  float* offo    = alloc_f((size_t)BQ_ * 128);
  float* awo     = alloc_f((size_t)BQ_ * 128);
  float* off_base= alloc_f((size_t)BQ_ * 128);
  float* aw_base = alloc_f((size_t)BQ_ * 128);
  float* c0      = alloc_f((size_t)BQ_ * D_);
  float* c1      = alloc_f((size_t)BQ_ * D_);
  float* m_sb    = alloc_f((size_t)NSTEP * BQ_ * 96);
  float* s_sb    = alloc_f((size_t)NSTEP * BQ_ * 96);
  unsigned short* hall    = alloc_u((size_t)(NSTEP + 1) * BQ_ * D_);  // h_0..h_15
  unsigned short* attnbf  = alloc_u((size_t)BQ_ * D_);
  unsigned short* qbf     = alloc_u((size_t)BQ_ * D_);
  unsigned short* ctxWbf  = alloc_u((size_t)512 * 64);
  unsigned short* xembbf  = alloc_u((size_t)NSTEP * BQ_ * D_);
  unsigned short* gates_base = alloc_u((size_t)NSTEP * BQ_ * 2048);
  unsigned short* logitWbf = alloc_u((size_t)V_ * D_);
  unsigned short* Wihbf    = alloc_u((size_t)2048 * 1536);
  unsigned short* Whhbf    = alloc_u((size_t)2048 * 512);
  unsigned short* offWbf   = alloc_u((size_t)128 * 1024);
  unsigned short* awWbf    = alloc_u((size_t)128 * 1024);
  unsigned short* hsWbf    = alloc_u((size_t)512 * 512);
  unsigned short* valueWbf = alloc_u((size_t)512 * 512);

  // one-time
  k_prep<<<11984, 256, 0, stream>>>(logitW, Wih, Whh, offW, awW, hsW, valueW, query, ctxW,
                                    seq, embedW,
                                    logitWbf, Wihbf, Whhbf, offWbf, awWbf, hsWbf,
                                    valueWbf, qbf, ctxWbf, hall, c0, xembbf);
  k_value<<<480, 256, 0, stream>>>(enc, valueWbf, valueb, mask, value);
  k_qg<<<242, 256, 0, stream>>>(qbf, offWbf, offb, awWbf, awb, off_base, aw_base,
                                xembbf, Wihbf, gates_base);

  float* cb[2] = {c0, c1};
  float* outp = (float*)d_out;

  // recurrence loop: only small kernels on the critical chain
  for (int t = 0; t < NSTEP; t++) {
    const unsigned short* hcur = hall + (size_t)t * BQ_ * D_;
    unsigned short* hnxt = hall + (size_t)(t + 1) * BQ_ * D_;
    if (t == 0)
      k_sample<<<1024, 256, 0, stream>>>(value, off_base, aw_base, hsb, 0, refp, vrat,
                                         ctxWbf, ctxb, alphaW, alphab, attnbf);
    else
      k_sample<<<1024, 256, 0, stream>>>(value, offo, awo, hproj, 512, refp, vrat,
                                         ctxWbf, ctxb, alphaW, alphab, attnbf);
    k_lstm_gemm<<<dim3(16, 4), 256, 0, stream>>>(attnbf, hcur, Wihbf, Whhbf, gpart);
    k_cell<<<256, 256, 0, stream>>>(gpart, gates_base + (size_t)t * BQ_ * 2048,
                                    cb[t & 1], cb[(t + 1) & 1], hnxt);
    if (t + 1 < NSTEP)
      k_pre<<<6, 256, 0, stream>>>(hnxt, offWbf, awWbf, hsWbf, hsb,
                                   off_base, aw_base, offo, awo, hproj);
  }

  // batched logits as one big GEMM + final lse subtract
  k_logits_big<<<1416, 256, 0, stream>>>(logitWbf, logitb, hall, outp, m_sb, s_sb);
  k_out_all<<<NSTEP * BQ_, 256, 0, stream>>>(m_sb, s_sb, outp);
}